// Round 2
// baseline (1392.170 us; speedup 1.0000x reference)
//
#include <hip/hip_runtime.h>
#include <hip/hip_bf16.h>

// NRDE layer, restructured (ALL inputs/outputs fp32 per reference; bf16 only for the
// precomputed A tensor + its MFMA GEMM):
//   A[a][b][h][w] = sum_d ml_w[w, h*136+d] * logsig[b, a, 1+d]   (big parallel GEMM, bf16 MFMA)
//   Abias[a][b][h] = sum_d ml_b[h*136+d]   * logsig[b, a, 1+d]   (fp32)
//   scan: 1 block per batch element b runs all 64 RK2 steps locally:
//   func(y) = h3 = tanh(relu(relu(y@W1+b1)@W2+b2)@W3+b3); k[h] = (h3 . A[a,b,h,:] + Abias)/dt
// times = arange(S+1) => searchsorted(t0=n)=clip(n,1,S) -> coeff idx max(n-1,0);
//                        searchsorted(t1=n+1)=n+1        -> coeff idx n.

#define BB 128
#define SS 64
#define LL 137
#define HH 128
#define DIN 64
#define WW 256
#define DD 136          // L-1
#define KP 160          // K padded to 5*32 for MFMA
#define NC 32768        // H*W output columns of the A-GEMM
#define OUT2_OFF ((size_t)BB*(SS+1)*HH)   // 1064960

typedef __hip_bfloat16 bf16;
typedef __attribute__((ext_vector_type(8))) short short8;
typedef __attribute__((ext_vector_type(4))) float f32x4;

__device__ __forceinline__ float bf2f(bf16 x) { return __bfloat162float(x); }
__device__ __forceinline__ bf16  f2bf(float x){ return __float2bfloat16(x); }
// unpack 2 bf16 packed in a uint (little-endian: low half = first element)
__device__ __forceinline__ float2 upk(unsigned u){
  float2 r;
  r.x = __uint_as_float(u << 16);
  r.y = __uint_as_float(u & 0xffff0000u);
  return r;
}

// ---------------- prep: coeff rows m=a*128+b (fp32 -> bf16), K padded to 160 with zeros ----------------
__global__ void prep_coeff(const float* __restrict__ logsig, bf16* __restrict__ cA){
  int m = blockIdx.x;            // 0..8191
  int d = threadIdx.x;           // 0..159
  int a = m >> 7, b = m & 127;
  float v = 0.0f;
  if (d < DD) v = logsig[(size_t)(b*SS + a)*LL + 1 + d];
  cA[(size_t)m*KP + d] = f2bf(v);
}

// ---------------- prep: Btt[c][d] = ml_w[w][h*136+d] (fp32 -> bf16), c = h*256+w ----------------
__global__ void prep_btt(const float* __restrict__ mlw, bf16* __restrict__ btt){
  int c = blockIdx.x;            // 0..32767
  int d = threadIdx.x;           // 0..159
  int h = c >> 8, w = c & 255;
  float v = 0.0f;
  if (d < DD) v = mlw[(size_t)w*(HH*DD) + h*DD + d];
  btt[(size_t)c*KP + d] = f2bf(v);
}

// ---------------- Abias[a][b][h] = ml_b[h*136:+136] . coeff[b,a,:] (all fp32) ----------------
__global__ void abias_kernel(const float* __restrict__ mlb, const float* __restrict__ logsig,
                             float* __restrict__ Abias){
  int a = blockIdx.x, b = blockIdx.y;
  int h = threadIdx.x;           // 128
  __shared__ float cf[DD];
  for (int d = h; d < DD; d += HH) cf[d] = logsig[(size_t)(b*SS + a)*LL + 1 + d];
  __syncthreads();
  float acc = 0.f;
  const float* mb = mlb + (size_t)h*DD;
  #pragma unroll 8
  for (int d = 0; d < DD; ++d) acc += cf[d] * mb[d];
  Abias[((size_t)a*BB + b)*HH + h] = acc;
}

// ---------------- A-GEMM: As[mLoc][c] = sum_d cA[mAbs][d]*btt[c][d], MFMA 16x16x32 bf16 ----------------
// Block tile 64(M) x 128(N); 4 waves, each 32x64 (2 Mfrag x 4 Nfrag). K = 5 chunks of 32.
// Fragment layouts (gfx950): A[m=lane&15][k=(lane>>4)*8+j]; B[k=(lane>>4)*8+j][n=lane&15];
// D[row=(lane>>4)*4+r][col=lane&15].
#define AST 40   // LDS k-stride (elements): 32 + 8 pad -> 80B rows, 16B aligned
__global__ __launch_bounds__(256) void agemm_kernel(const bf16* __restrict__ cA,
                                                    const bf16* __restrict__ btt,
                                                    bf16* __restrict__ As, int mAbs0){
  __shared__ __align__(16) short a_sm[64*AST];
  __shared__ __align__(16) short b_sm[128*AST];
  __shared__ __align__(16) short o_sm[64*136];   // 128 cols + 8 pad
  int mt = blockIdx.x, nt = blockIdx.y;
  int t = threadIdx.x, lane = t & 63, wid = t >> 6;
  int mBlockAbs = mAbs0 + mt*64;
  int c0 = nt*128;
  int mW = (wid & 1)*32, cW = (wid >> 1)*64;

  f32x4 acc[2][4];
  for (int i = 0; i < 2; ++i)
    for (int j = 0; j < 4; ++j)
      acc[i][j] = (f32x4){0.f,0.f,0.f,0.f};

  for (int kk = 0; kk < 5; ++kk){
    int d0 = kk*32;
    { // stage A: 64 rows x 32 d = 256 x 16B
      int row = t >> 2, seg = t & 3;
      uint4 v = *(const uint4*)(cA + (size_t)(mBlockAbs+row)*KP + d0 + seg*8);
      *(uint4*)&a_sm[row*AST + seg*8] = v;
    }
    #pragma unroll
    for (int rep = 0; rep < 2; ++rep){ // stage B: 128 rows x 32 d = 512 x 16B
      int idx = t + rep*256;
      int row = idx >> 2, seg = idx & 3;
      uint4 v = *(const uint4*)(btt + (size_t)(c0+row)*KP + d0 + seg*8);
      *(uint4*)&b_sm[row*AST + seg*8] = v;
    }
    __syncthreads();
    int mr = lane & 15, q = lane >> 4;
    short8 af[2], bfr[4];
    #pragma unroll
    for (int mi = 0; mi < 2; ++mi) af[mi]  = *(const short8*)&a_sm[(mW + mi*16 + mr)*AST + q*8];
    #pragma unroll
    for (int ci = 0; ci < 4; ++ci) bfr[ci] = *(const short8*)&b_sm[(cW + ci*16 + mr)*AST + q*8];
    #pragma unroll
    for (int mi = 0; mi < 2; ++mi)
      #pragma unroll
      for (int ci = 0; ci < 4; ++ci)
        acc[mi][ci] = __builtin_amdgcn_mfma_f32_16x16x32_bf16(af[mi], bfr[ci], acc[mi][ci], 0, 0, 0);
    __syncthreads();
  }

  // epilogue: regs -> LDS (bf16) -> coalesced 16B stores
  {
    int mr = lane & 15, q = lane >> 4;
    #pragma unroll
    for (int mi = 0; mi < 2; ++mi)
      #pragma unroll
      for (int ci = 0; ci < 4; ++ci){
        int col = cW + ci*16 + mr;
        #pragma unroll
        for (int r = 0; r < 4; ++r){
          int row = mW + mi*16 + q*4 + r;
          bf16 bv = f2bf(acc[mi][ci][r]);
          o_sm[row*136 + col] = *(short*)&bv;
        }
      }
  }
  __syncthreads();
  int mLocBlock = mt*64;
  #pragma unroll
  for (int rep = 0; rep < 4; ++rep){
    int idx = t + rep*256;
    int row = idx >> 4, seg = idx & 15;
    uint4 v = *(const uint4*)&o_sm[row*136 + seg*8];
    *(uint4*)(As + (size_t)(mLocBlock + row)*NC + c0 + seg*8) = v;
  }
}

// ---------------- scan: one block per batch element, 512 threads (8 waves) ----------------
__device__ __forceinline__ void nrde_func(
    int b, int t,
    const float* __restrict__ yin, float* __restrict__ bufA, float* __restrict__ bufB,
    float* __restrict__ part,
    const float* __restrict__ h1_w, const float* __restrict__ h1_b,
    const float* __restrict__ h2_w, const float* __restrict__ h2_b,
    const float* __restrict__ vo_w, const float* __restrict__ vo_b,
    const bf16* __restrict__ As, const float* __restrict__ Abias,
    int aLoc, int aAbs, float inv_dtf, float* __restrict__ kout)
{
  int j = t & 255, half = t >> 8;     // 512 threads: j = output col, half = K-split
  // L1: 128 -> 256, relu
  {
    float acc = 0.f;
    const float* in = yin + half*64;
    const float* w = h1_w + (size_t)(half*64)*WW + j;
    #pragma unroll 4
    for (int i = 0; i < 64; i += 4){
      float4 y4 = *(const float4*)&in[i];
      acc += y4.x * w[(size_t)(i+0)*WW];
      acc += y4.y * w[(size_t)(i+1)*WW];
      acc += y4.z * w[(size_t)(i+2)*WW];
      acc += y4.w * w[(size_t)(i+3)*WW];
    }
    part[t] = acc;
  }
  __syncthreads();
  if (t < WW){
    float v = h1_b[t] + part[t] + part[t+256];
    bufA[t] = v > 0.f ? v : 0.f;
  }
  __syncthreads();
  // L2: 256 -> 256, relu
  {
    float acc = 0.f;
    const float* in = bufA + half*128;
    const float* w = h2_w + (size_t)(half*128)*WW + j;
    #pragma unroll 4
    for (int i = 0; i < 128; i += 4){
      float4 x4 = *(const float4*)&in[i];
      acc += x4.x * w[(size_t)(i+0)*WW];
      acc += x4.y * w[(size_t)(i+1)*WW];
      acc += x4.z * w[(size_t)(i+2)*WW];
      acc += x4.w * w[(size_t)(i+3)*WW];
    }
    part[t] = acc;
  }
  __syncthreads();
  if (t < WW){
    float v = h2_b[t] + part[t] + part[t+256];
    bufB[t] = v > 0.f ? v : 0.f;
  }
  __syncthreads();
  // L3: 256 -> 256, tanh
  {
    float acc = 0.f;
    const float* in = bufB + half*128;
    const float* w = vo_w + (size_t)(half*128)*WW + j;
    #pragma unroll 4
    for (int i = 0; i < 128; i += 4){
      float4 x4 = *(const float4*)&in[i];
      acc += x4.x * w[(size_t)(i+0)*WW];
      acc += x4.y * w[(size_t)(i+1)*WW];
      acc += x4.z * w[(size_t)(i+2)*WW];
      acc += x4.w * w[(size_t)(i+3)*WW];
    }
    part[t] = acc;
  }
  __syncthreads();
  if (t < WW){
    float v = vo_b[t] + part[t] + part[t+256];
    bufA[t] = tanhf(v);
  }
  __syncthreads();
  // matvec: k[h] = sum_w h3[w]*A[aLoc][b][h][w]  (A streamed from global, bf16, 16B loads)
  {
    int h = t & 127, q4 = t >> 7;    // q4 = w-quarter
    const bf16* Arow = As + (((size_t)aLoc*BB + b)*HH + h)*WW + q4*64;
    const float* hv = bufA + q4*64;
    float s = 0.f;
    #pragma unroll
    for (int w8 = 0; w8 < 8; ++w8){
      uint4 u = *(const uint4*)(Arow + w8*8);
      float2 p;
      p = upk(u.x); s += hv[w8*8+0]*p.x + hv[w8*8+1]*p.y;
      p = upk(u.y); s += hv[w8*8+2]*p.x + hv[w8*8+3]*p.y;
      p = upk(u.z); s += hv[w8*8+4]*p.x + hv[w8*8+5]*p.y;
      p = upk(u.w); s += hv[w8*8+6]*p.x + hv[w8*8+7]*p.y;
    }
    part[t] = s;
  }
  __syncthreads();
  if (t < HH){
    float s = part[t] + part[t+128] + part[t+256] + part[t+384]
            + Abias[((size_t)aAbs*BB + b)*HH + t];
    kout[t] = s * inv_dtf;
  }
  // caller syncs before consuming kout
}

__global__ __launch_bounds__(512) void scan_kernel(
    const float* __restrict__ times, const float* __restrict__ initial,
    const float* __restrict__ in_w, const float* __restrict__ in_b,
    const float* __restrict__ h1_w, const float* __restrict__ h1_b,
    const float* __restrict__ h2_w, const float* __restrict__ h2_b,
    const float* __restrict__ vo_w, const float* __restrict__ vo_b,
    const bf16* __restrict__ As, const float* __restrict__ Abias,
    float* __restrict__ y_state, float* __restrict__ out,
    int s0, int s1, int aBase)
{
  const int b = blockIdx.x, t = threadIdx.x;
  __shared__ float yv[HH], ytmp[HH], bufA[WW], bufB[WW], kk1[HH], kk2[HH];
  __shared__ float part[512];

  if (s0 == 0){
    if (t < HH){
      float acc = in_b[t];
      for (int i = 0; i < DIN; ++i)
        acc += initial[b*DIN + i] * in_w[(size_t)i*HH + t];
      yv[t] = acc;
      out[((size_t)b*(SS+1))*HH + t] = acc;
    }
  } else {
    if (t < HH) yv[t] = y_state[b*HH + t];
  }
  __syncthreads();

  for (int n = s0; n < s1; ++n){
    float t0 = times[n], t1 = times[n+1];
    float dt = t1 - t0;
    int idx1 = (n >= 1) ? n : 1;              // clip(searchsorted(times, t0), 1, S)
    float dtf1 = times[idx1] - times[idx1-1];
    int a1 = (n >= 1) ? (n-1) : 0;
    // k1 = func(t0, y)
    nrde_func(b, t, yv, bufA, bufB, part, h1_w, h1_b, h2_w, h2_b, vo_w, vo_b,
              As, Abias, a1 - aBase, a1, 1.f/dtf1, kk1);
    __syncthreads();
    if (t < HH) ytmp[t] = yv[t] + dt*kk1[t];
    __syncthreads();
    // k2 = func(t1, y + dt*k1), coeff idx n, dtf = times[n+1]-times[n] = dt
    nrde_func(b, t, ytmp, bufA, bufB, part, h1_w, h1_b, h2_w, h2_b, vo_w, vo_b,
              As, Abias, n - aBase, n, 1.f/dt, kk2);
    __syncthreads();
    if (t < HH){
      float ynew = yv[t] + 0.5f*dt*(kk1[t] + kk2[t]);
      yv[t] = ynew;
      out[((size_t)b*(SS+1) + (n+1))*HH + t] = ynew;
    }
    __syncthreads();
  }

  if (t < HH){
    y_state[b*HH + t] = yv[t];
    if (s1 == SS) out[OUT2_OFF + (size_t)b*HH + t] = yv[t];
  }
}

extern "C" void kernel_launch(void* const* d_in, const int* in_sizes, int n_in,
                              void* d_out, int out_size, void* d_ws, size_t ws_size,
                              hipStream_t stream)
{
  (void)in_sizes; (void)n_in; (void)out_size;
  const float* times   = (const float*)d_in[0];
  const float* logsig  = (const float*)d_in[1];
  const float* initial = (const float*)d_in[2];
  const float* in_w    = (const float*)d_in[3];
  const float* in_b    = (const float*)d_in[4];
  const float* h1_w    = (const float*)d_in[5];
  const float* h1_b    = (const float*)d_in[6];
  const float* h2_w    = (const float*)d_in[7];
  const float* h2_b    = (const float*)d_in[8];
  const float* vo_w    = (const float*)d_in[9];
  const float* vo_b    = (const float*)d_in[10];
  const float* ml_w    = (const float*)d_in[11];
  const float* ml_b    = (const float*)d_in[12];
  float* out = (float*)d_out;

  char* ws = (char*)d_ws;
  size_t off = 0;
  bf16* cA      = (bf16*)(ws + off); off += (size_t)8192*KP*2;        // 2.62 MB
  bf16* btt     = (bf16*)(ws + off); off += (size_t)NC*KP*2;          // 10.49 MB
  float* Abias  = (float*)(ws + off); off += (size_t)SS*BB*HH*4;      // 4.19 MB
  float* y_state= (float*)(ws + off); off += (size_t)BB*HH*4;         // 64 KB
  bf16* As      = (bf16*)(ws + off);
  size_t perA = (size_t)BB*HH*WW*2;                                   // 16.78 MB per a-index
  size_t avail = (ws_size > off) ? (ws_size - off) : 0;
  int C = (int)(avail / perA);
  if (C > SS) C = SS;
  if (C < 2) return;  // workspace too small for even a 2-step A chunk -> fail loudly

  prep_coeff<<<8192, 160, 0, stream>>>(logsig, cA);
  prep_btt<<<NC, 160, 0, stream>>>(ml_w, btt);
  abias_kernel<<<dim3(SS, BB), HH, 0, stream>>>(ml_b, logsig, Abias);

  // Chunked over A-indices; consecutive chunks overlap by 1 (step n needs A[n-1] and A[n]).
  int s = 0, aB = 0;
  while (s < SS){
    int cc = SS - aB; if (cc > C) cc = C;
    agemm_kernel<<<dim3(cc*2, 256), 256, 0, stream>>>(cA, btt, As, aB*BB);
    int sEnd = aB + cc; if (sEnd > SS) sEnd = SS;
    scan_kernel<<<BB, 512, 0, stream>>>(times, initial, in_w, in_b, h1_w, h1_b,
        h2_w, h2_b, vo_w, vo_b, As, Abias, y_state, out, s, sEnd, aB);
    s = sEnd;
    aB = sEnd - 1;
  }
}